// Round 5
// baseline (309.378 us; speedup 1.0000x reference)
//
#include <hip/hip_runtime.h>

typedef __bf16 bf16x8 __attribute__((ext_vector_type(8)));
typedef __bf16 bf16x4 __attribute__((ext_vector_type(4)));
typedef float f32x4 __attribute__((ext_vector_type(4)));

__device__ __forceinline__ unsigned short f2b(float f) {
    unsigned int u = __float_as_uint(f);
    return (unsigned short)((u + 0x7fffu + ((u >> 16) & 1u)) >> 16);  // RNE
}

// ---------------------------------------------------------------------------
// Prep (unchanged, correctness-proven): fold W_nl into W_out, emit bf16 W'
// in MFMA fragment order [ct][ks][lane][j], plus fused bias
// b'[o] = b_out[o] + sum_f b_nl[f]*W_out[o,f].
// ---------------------------------------------------------------------------
__global__ __launch_bounds__(256) void wk_prep(
    const float* __restrict__ Wnl, const float* __restrict__ bnl,
    const float* __restrict__ Wout, const float* __restrict__ bout,
    unsigned short* __restrict__ wfrag, float* __restrict__ wbias) {
    int b = blockIdx.x, tid = threadIdx.x;
    if (b < 256) {
        int t = b * 256 + tid;
        int j = t & 7;
        int lane = (t >> 3) & 63;
        int ks = (t >> 9) & 7;
        int ct = t >> 12;                       // col-tile 0..15
        int f = ks * 32 + ((lane >> 4) << 3) + j;
        int o = ct * 16 + (lane & 15);
        float c = 0.70710678f * (Wnl[2 * f] + Wnl[2 * f + 1]);
        wfrag[t] = f2b(c * Wout[o * 256 + f]);
    } else {
        int o = tid;
        const float4* wr = (const float4*)(Wout + o * 256);
        const float4* bn = (const float4*)bnl;
        float s = 0.f;
        #pragma unroll 4
        for (int i = 0; i < 64; ++i) {
            float4 a = bn[i], b4 = wr[i];
            s += a.x * b4.x + a.y * b4.y + a.z * b4.z + a.w * b4.w;
        }
        wbias[o] = bout[o] + s;
    }
}

// ---------------------------------------------------------------------------
// Round 5: the two invariants shared by all ~100 us rounds are removed.
// (1) LINEAR STORES: MFMA D-fragments (lane&15 = out ROW -> 16-row scatter of
//     16-B chunks per store instr in every previous round) now go to a 32-KB
//     LDS staging buffer (lane-linear ds_write_b128, conflict-free by
//     construction; XOR-swizzle (S&7)<<4 makes the transposed re-read land
//     exactly 8 dwords/bank = b128 floor). Global stores become 8-KB dense
//     contiguous runs per instruction — the same stream shape the harness's
//     fill kernel drives at 6.5 TB/s on this chip.
// (2) PREFETCH DEPTH 2: two register staging buffers, statically unrolled x2
//     (rule #20), so x loads are issued two full tiles (~1200 cyc) before
//     their convert — deeper than HBM latency (~900 cyc); depth-1 stalled
//     every wave ~300+ cyc per tile, barrier-synchronized.
// Geometry unchanged from the PASSED round-4 kernel: 512 blocks x 512 thr,
// 32-row tiles, bf16 Xlds [2][32][576 B] (convert-once, conflict-free),
// W' in registers (wave owns 2 col-tiles). LDS 68 KB -> 2 blocks/CU.
// ---------------------------------------------------------------------------
__global__ __launch_bounds__(512, 4) void wk_main(
    const float* __restrict__ x, const unsigned short* __restrict__ wfrag,
    const float* __restrict__ wbias, float* __restrict__ out) {
    const int tid  = threadIdx.x;
    const int lane = tid & 63;
    const int w    = tid >> 6;          // wave 0..7
    const int m    = lane & 15;
    const int quad = lane >> 4;

    __shared__ char Xlds[2][18432];     // [p][row(32)][576 B: 512 data + 64 pad]
    __shared__ char Olds[32768];        // [S(16)][mt(2)][lane(64)][16 B], swizzled

    const int b  = blockIdx.x;
    const int t0 = (b * 5000) >> 9;     // 32-row tiles, 5000 total
    const int t1 = ((b + 1) * 5000) >> 9;

    // --- W' fragments (2 adjacent col-tiles) + fused bias, in registers ---
    int4  Wf[2][8];
    f32x4 bias[2];
    {
        const int4* ws = (const int4*)wfrag;
        #pragma unroll
        for (int c2 = 0; c2 < 2; ++c2) {
            #pragma unroll
            for (int ks = 0; ks < 8; ++ks)
                Wf[c2][ks] = ws[(((2 * w + c2) * 8 + ks) << 6) + lane];
            bias[c2] = *(const f32x4*)(wbias + (2 * w + c2) * 16 + quad * 4);
        }
    }

    // --- depth-2 register staging: wave w, step s -> row s*8+w; lane covers
    //     16-B chunk `lane` of the 1-KB row (block reads 32 KB contiguous) ---
    f32x4 sbufA[4], sbufB[4];
    #define LOADT(SB, T)                                                      \
        {                                                                     \
            const f32x4* xt = (const f32x4*)x + (size_t)(T) * 2048;           \
            _Pragma("unroll")                                                 \
            for (int s = 0; s < 4; ++s)                                       \
                SB[s] = xt[s * 512 + w * 64 + lane];                          \
        }

    LOADT(sbufA, t0);
    LOADT(sbufB, t0 + 1);               // t1-t0 >= 9, always in range

    int p = 0;
    int t = t0;

    #define STEP(SB)                                                          \
    {                                                                         \
        /* convert once, write bf16 rows into Xlds[p] (conflict-free) */      \
        {                                                                     \
            char* dst = Xlds[p] + w * 576 + lane * 8;                         \
            _Pragma("unroll")                                                 \
            for (int s = 0; s < 4; ++s) {                                     \
                f32x4 u = SB[s];                                              \
                bf16x4 h;                                                     \
                h[0] = (__bf16)u[0]; h[1] = (__bf16)u[1];                     \
                h[2] = (__bf16)u[2]; h[3] = (__bf16)u[3];                     \
                *(bf16x4*)(dst + s * 4608) = h;                               \
            }                                                                 \
        }                                                                     \
        if (t + 2 < t1) LOADT(SB, t + 2);   /* depth-2 prefetch */            \
        asm volatile("s_waitcnt lgkmcnt(0)" ::: "memory");                    \
        __builtin_amdgcn_s_barrier();                                         \
        __builtin_amdgcn_sched_barrier(0);                                    \
        /* compute tile t; D goes to Olds, not global */                      \
        {                                                                     \
            const char* src = Xlds[p] + m * 576 + quad * 16;                  \
            _Pragma("unroll")                                                 \
            for (int mt = 0; mt < 2; ++mt) {                                  \
                f32x4 a0 = bias[0], a1 = bias[1];                             \
                _Pragma("unroll")                                             \
                for (int ks = 0; ks < 8; ++ks) {                              \
                    bf16x8 afr = *(const bf16x8*)(src + mt * 9216 + ks * 64); \
                    a0 = __builtin_amdgcn_mfma_f32_16x16x32_bf16(             \
                        __builtin_bit_cast(bf16x8, Wf[0][ks]), afr, a0,0,0,0);\
                    a1 = __builtin_amdgcn_mfma_f32_16x16x32_bf16(             \
                        __builtin_bit_cast(bf16x8, Wf[1][ks]), afr, a1,0,0,0);\
                }                                                             \
                const int S0 = 2 * w, S1 = 2 * w + 1;                         \
                *(f32x4*)(Olds + ((S0 * 2048 + mt * 1024 + lane * 16)         \
                                  ^ ((S0 & 7) << 4))) = a0;                   \
                *(f32x4*)(Olds + ((S1 * 2048 + mt * 1024 + lane * 16)         \
                                  ^ ((S1 & 7) << 4))) = a1;                   \
            }                                                                 \
        }                                                                     \
        asm volatile("s_waitcnt lgkmcnt(0)" ::: "memory");                    \
        __builtin_amdgcn_s_barrier();                                         \
        __builtin_amdgcn_sched_barrier(0);                                    \
        /* transposed re-read (8 dwords/bank) -> dense 8-KB global stores */  \
        {                                                                     \
            float* ob = out + (size_t)t * 8192;                               \
            _Pragma("unroll")                                                 \
            for (int it = 0; it < 4; ++it) {                                  \
                const int R = it * 8 + w;         /* out row in tile */       \
                const int mtr = R >> 4, mr = R & 15;                          \
                const int Sr = lane >> 2;                                     \
                f32x4 v = *(const f32x4*)(Olds +                              \
                    ((Sr * 2048 + mtr * 1024 + ((lane & 3) * 16 + mr) * 16)   \
                     ^ ((Sr & 7) << 4)));                                     \
                *(f32x4*)(ob + it * 2048 + tid * 4) = v;                      \
            }                                                                 \
        }                                                                     \
        p ^= 1;                                                               \
    }

    for (;;) {
        STEP(sbufA);
        if (++t == t1) break;
        STEP(sbufB);
        if (++t == t1) break;
    }
    #undef STEP
    #undef LOADT
}

extern "C" void kernel_launch(void* const* d_in, const int* in_sizes, int n_in,
                              void* d_out, int out_size, void* d_ws, size_t ws_size,
                              hipStream_t stream) {
    const float* x    = (const float*)d_in[0];   // [8,20000,256]
    const float* Wnl  = (const float*)d_in[1];   // [256,2]
    const float* bnl  = (const float*)d_in[2];   // [256]
    const float* Wout = (const float*)d_in[3];   // [256,256]
    const float* bout = (const float*)d_in[4];   // [256]

    unsigned short* wfrag = (unsigned short*)d_ws;            // 65536 bf16 = 128 KB
    float* wbias = (float*)((char*)d_ws + 131072);            // 256 f32

    wk_prep<<<257, 256, 0, stream>>>(Wnl, bnl, Wout, bout, wfrag, wbias);
    wk_main<<<512, 512, 0, stream>>>(x, wfrag, wbias, (float*)d_out);
}